// Round 7
// baseline (118.517 us; speedup 1.0000x reference)
//
#include <hip/hip_runtime.h>
#include <hip/hip_bf16.h>
#include <math.h>

// GAT forward, N=4096, F=512, H=8, NH=64.
// Round 7: layer-2 algebraic refactor — att2@(hcat@Wo) = (att2@hcat)@Wo,
// s2 = hcat·(Wo@ao1). Kills the Who round-trip; gemm2 writes out with fused
// ELU. 5 launches: prep, gemm1(+s1/d1), attn8(+s2/d2), attn1(agg2), gemm2(ELU).

#define GN 4096
#define GF 512

typedef __attribute__((ext_vector_type(8))) short bf16x8;
typedef __attribute__((ext_vector_type(4))) float f32x4;

__device__ inline unsigned short f2bf(float f) {
    unsigned u = __float_as_uint(f);
    return (unsigned short)((u + 0x7fffu + ((u >> 16) & 1u)) >> 16);
}
__device__ inline float bf2f(unsigned short h) {
    return __uint_as_float((unsigned)h << 16);
}
__device__ inline void split2(float v, unsigned short& h, unsigned short& l) {
    h = f2bf(v);
    l = f2bf(v - bf2f(h));
}
__device__ inline void gl16(const void* g, void* l) {
    __builtin_amdgcn_global_load_lds((const __attribute__((address_space(1))) unsigned int*)g,
                                     (__attribute__((address_space(3))) unsigned int*)l, 16, 0, 0);
}

// ---- fused prep: extract_nbrs + packs + split x + wo1/wo2 GEMV ----
// grid = 4096 + 64 + 64 + 2048 + 8 = 6280
__global__ __launch_bounds__(256) void prep(
        const float* __restrict__ adj, const float* __restrict__ Ws,
        const float* __restrict__ Wo, const float* __restrict__ x,
        const float* __restrict__ ao1, const float* __restrict__ ao2,
        unsigned short* __restrict__ nbr, int* __restrict__ deg,
        unsigned short* __restrict__ wshi, unsigned short* __restrict__ wslo,
        unsigned short* __restrict__ wohi, unsigned short* __restrict__ wolo,
        unsigned short* __restrict__ xhi, unsigned short* __restrict__ xlo,
        float* __restrict__ wo1v, float* __restrict__ wo2v, int N) {
    __shared__ int wtot[4];
    __shared__ int wbase[4];
    __shared__ float T[64][65];
    int b = blockIdx.x;
    const int t = threadIdx.x;
    if (b < 4096) {                       // neighbor extraction, row = b
        const int lane = t & 63, wid = t >> 6, row = b;
        const float4* arow = (const float4*)(adj + (size_t)row * N);
        unsigned mask16 = 0;
        #pragma unroll
        for (int q = 0; q < 4; ++q) {
            float4 v = arow[t * 4 + q];
            if (v.x > 0.f) mask16 |= 1u << (q * 4 + 0);
            if (v.y > 0.f) mask16 |= 1u << (q * 4 + 1);
            if (v.z > 0.f) mask16 |= 1u << (q * 4 + 2);
            if (v.w > 0.f) mask16 |= 1u << (q * 4 + 3);
        }
        int cnt = __popc(mask16);
        int inc = cnt;
        #pragma unroll
        for (int off = 1; off < 64; off <<= 1) {
            int nv = __shfl_up(inc, off);
            if (lane >= off) inc += nv;
        }
        if (lane == 63) wtot[wid] = inc;
        __syncthreads();
        if (t == 0) {
            int s = 0;
            #pragma unroll
            for (int w = 0; w < 4; ++w) { wbase[w] = s; s += wtot[w]; }
            deg[row] = s;
        }
        __syncthreads();
        int base = wbase[wid] + inc - cnt;
        unsigned short* dst = nbr + (size_t)row * 512 + base;
        int col0 = t * 16;
        int k = 0;
        while (mask16) {
            int bi = __ffs(mask16) - 1;
            mask16 &= mask16 - 1;
            dst[k++] = (unsigned short)(col0 + bi);
        }
        return;
    }
    b -= 4096;
    if (b < 64) {                         // Ws[h][f][k] -> Bt[h*64+k][f], tiled
        const int h = b >> 3, f0 = (b & 7) * 64;
        #pragma unroll
        for (int i = 0; i < 16; ++i) {
            int idx = i * 256 + t;
            int fr = idx >> 6, k = idx & 63;
            T[fr][k] = Ws[h * 32768 + (f0 + fr) * 64 + k];
        }
        __syncthreads();
        #pragma unroll
        for (int i = 0; i < 16; ++i) {
            int idx = i * 256 + t;
            int k = idx >> 6, fr = idx & 63;
            unsigned short hh, ll;
            split2(T[fr][k], hh, ll);
            size_t dst = (size_t)(h * 64 + k) * 512 + f0 + fr;
            wshi[dst] = hh; wslo[dst] = ll;
        }
        return;
    }
    b -= 64;
    if (b < 64) {                         // Wo[f][c] -> Bt[c][f], tiled
        const int c0 = (b >> 3) * 64, f0 = (b & 7) * 64;
        #pragma unroll
        for (int i = 0; i < 16; ++i) {
            int idx = i * 256 + t;
            int fr = idx >> 6, k = idx & 63;
            T[fr][k] = Wo[(size_t)(f0 + fr) * 512 + c0 + k];
        }
        __syncthreads();
        #pragma unroll
        for (int i = 0; i < 16; ++i) {
            int idx = i * 256 + t;
            int k = idx >> 6, fr = idx & 63;
            unsigned short hh, ll;
            split2(T[fr][k], hh, ll);
            size_t dst = (size_t)(c0 + k) * 512 + f0 + fr;
            wohi[dst] = hh; wolo[dst] = ll;
        }
        return;
    }
    b -= 64;
    if (b < 2048) {                       // split x -> hi/lo
        int i = b * 256 + t;              // [0, 524288)
        float4 v = ((const float4*)x)[i];
        ushort4 h, l;
        split2(v.x, h.x, l.x); split2(v.y, h.y, l.y);
        split2(v.z, h.z, l.z); split2(v.w, h.w, l.w);
        ((ushort4*)xhi)[i] = h;
        ((ushort4*)xlo)[i] = l;
        return;
    }
    b -= 2048;
    {                                     // wo1 = Wo@ao1, wo2 = Wo@ao2 (8 blocks)
        const int r = b * 64 + (t >> 2);  // row of Wo
        const int q = t & 3;              // quarter of the 512 cols
        const float4* wr = (const float4*)(Wo + (size_t)r * 512 + q * 128);
        const float4* a1r = (const float4*)(ao1 + q * 128);
        const float4* a2r = (const float4*)(ao2 + q * 128);
        float s1 = 0.f, s2v = 0.f;
        #pragma unroll
        for (int i = 0; i < 32; ++i) {
            float4 w = wr[i], u = a1r[i], v = a2r[i];
            s1  += w.x * u.x + w.y * u.y + w.z * u.z + w.w * u.w;
            s2v += w.x * v.x + w.y * v.y + w.z * v.z + w.w * v.w;
        }
        s1  += __shfl_xor(s1, 1);  s1  += __shfl_xor(s1, 2);
        s2v += __shfl_xor(s2v, 1); s2v += __shfl_xor(s2v, 2);
        if (q == 0) { wo1v[r] = s1; wo2v[r] = s2v; }
    }
}

// ---- MFMA GEMM: C = A@B; A hi/lo [M][K], B hi/lo [Nc][K]; 64x64 tile, BK=64,
// double-buffered LDS, 3-term bf16 split.
// EPI=0: write C f32 + fused s/d per-head dots (layer 1; bn block == head).
// EPI=1: write elu(acc) to C (final output, layer 2).
template<int EPI>
__global__ __launch_bounds__(256) void gemm_3t(
        const unsigned short* __restrict__ Ahi, const unsigned short* __restrict__ Alo,
        const unsigned short* __restrict__ Bhi, const unsigned short* __restrict__ Blo,
        const float* __restrict__ a1v, const float* __restrict__ a2v,
        float* __restrict__ C, float* __restrict__ sdst, float* __restrict__ ddst,
        int M, int K, int Nc) {
    __shared__ char lds[65536];           // 2 buffers x 32KB (Ah|Al|Bh|Bl)
    const int t = threadIdx.x, lane = t & 63, wid = t >> 6;
    const int bm0 = blockIdx.y * 64, bn0 = blockIdx.x * 64;
    const int r0 = t >> 3;
    const int sc8 = (((t & 7) ^ ((t >> 3) & 7)) << 3);   // swizzled chunk, elems
    const size_t aoff = (size_t)(bm0 + r0) * K + sc8;
    const size_t boff = (size_t)(bn0 + r0) * K + sc8;
    const size_t half = (size_t)32 * K;

    auto stage = [&](char* dst, int k0) {
        gl16(Ahi + aoff + k0,        dst + 0 * 4096 + t * 16);
        gl16(Ahi + aoff + half + k0, dst + 1 * 4096 + t * 16);
        gl16(Alo + aoff + k0,        dst + 2 * 4096 + t * 16);
        gl16(Alo + aoff + half + k0, dst + 3 * 4096 + t * 16);
        gl16(Bhi + boff + k0,        dst + 4 * 4096 + t * 16);
        gl16(Bhi + boff + half + k0, dst + 5 * 4096 + t * 16);
        gl16(Blo + boff + k0,        dst + 6 * 4096 + t * 16);
        gl16(Blo + boff + half + k0, dst + 7 * 4096 + t * 16);
    };

    f32x4 acc00 = {0,0,0,0}, acc01 = {0,0,0,0}, acc10 = {0,0,0,0}, acc11 = {0,0,0,0};
    const int mq = (wid >> 1) * 32, nq = (wid & 1) * 32;
    const int rl = lane & 15, hl = lane >> 4;
    const int swz = rl & 7;

    auto compute = [&](const char* Lb) {
        const char* Ah_ = Lb;
        const char* Al_ = Lb + 8192;
        const char* Bh_ = Lb + 16384;
        const char* Bl_ = Lb + 24576;
        #pragma unroll
        for (int s = 0; s < 2; ++s) {
            const int ch = ((s * 4 + hl) ^ swz) * 16;
            const int ra0 = (mq + rl) * 128, ra1 = ra0 + 16 * 128;
            const int rb0 = (nq + rl) * 128, rb1 = rb0 + 16 * 128;
            bf16x8 A0h = *(const bf16x8*)(Ah_ + ra0 + ch);
            bf16x8 A1h = *(const bf16x8*)(Ah_ + ra1 + ch);
            bf16x8 A0l = *(const bf16x8*)(Al_ + ra0 + ch);
            bf16x8 A1l = *(const bf16x8*)(Al_ + ra1 + ch);
            bf16x8 B0h = *(const bf16x8*)(Bh_ + rb0 + ch);
            bf16x8 B1h = *(const bf16x8*)(Bh_ + rb1 + ch);
            bf16x8 B0l = *(const bf16x8*)(Bl_ + rb0 + ch);
            bf16x8 B1l = *(const bf16x8*)(Bl_ + rb1 + ch);
            acc00 = __builtin_amdgcn_mfma_f32_16x16x32_bf16(A0h, B0h, acc00, 0, 0, 0);
            acc01 = __builtin_amdgcn_mfma_f32_16x16x32_bf16(A0h, B1h, acc01, 0, 0, 0);
            acc10 = __builtin_amdgcn_mfma_f32_16x16x32_bf16(A1h, B0h, acc10, 0, 0, 0);
            acc11 = __builtin_amdgcn_mfma_f32_16x16x32_bf16(A1h, B1h, acc11, 0, 0, 0);
            acc00 = __builtin_amdgcn_mfma_f32_16x16x32_bf16(A0h, B0l, acc00, 0, 0, 0);
            acc01 = __builtin_amdgcn_mfma_f32_16x16x32_bf16(A0h, B1l, acc01, 0, 0, 0);
            acc10 = __builtin_amdgcn_mfma_f32_16x16x32_bf16(A1h, B0l, acc10, 0, 0, 0);
            acc11 = __builtin_amdgcn_mfma_f32_16x16x32_bf16(A1h, B1l, acc11, 0, 0, 0);
            acc00 = __builtin_amdgcn_mfma_f32_16x16x32_bf16(A0l, B0h, acc00, 0, 0, 0);
            acc01 = __builtin_amdgcn_mfma_f32_16x16x32_bf16(A0l, B1h, acc01, 0, 0, 0);
            acc10 = __builtin_amdgcn_mfma_f32_16x16x32_bf16(A1l, B0h, acc10, 0, 0, 0);
            acc11 = __builtin_amdgcn_mfma_f32_16x16x32_bf16(A1l, B1h, acc11, 0, 0, 0);
        }
    };

    stage(lds, 0);
    __syncthreads();
    const int NT = K / 64;                // 8 steps
    for (int st = 0; st < NT; ++st) {
        char* cur = lds + (st & 1) * 32768;
        if (st + 1 < NT) stage(lds + ((st + 1) & 1) * 32768, (st + 1) * 64);
        compute(cur);
        __syncthreads();
    }

    const int orow = hl * 4;
    if constexpr (EPI == 1) {
        #pragma unroll
        for (int j = 0; j < 4; ++j) {
            float v0 = acc00[j], v1 = acc01[j], v2 = acc10[j], v3 = acc11[j];
            v0 = v0 > 0.f ? v0 : expm1f(v0);
            v1 = v1 > 0.f ? v1 : expm1f(v1);
            v2 = v2 > 0.f ? v2 : expm1f(v2);
            v3 = v3 > 0.f ? v3 : expm1f(v3);
            C[(size_t)(bm0 + mq + orow + j) * Nc + bn0 + nq + rl]           = v0;
            C[(size_t)(bm0 + mq + orow + j) * Nc + bn0 + nq + 16 + rl]      = v1;
            C[(size_t)(bm0 + mq + 16 + orow + j) * Nc + bn0 + nq + rl]      = v2;
            C[(size_t)(bm0 + mq + 16 + orow + j) * Nc + bn0 + nq + 16 + rl] = v3;
        }
        return;
    } else {
        #pragma unroll
        for (int j = 0; j < 4; ++j) {
            C[(size_t)(bm0 + mq + orow + j) * Nc + bn0 + nq + rl]           = acc00[j];
            C[(size_t)(bm0 + mq + orow + j) * Nc + bn0 + nq + 16 + rl]      = acc01[j];
            C[(size_t)(bm0 + mq + 16 + orow + j) * Nc + bn0 + nq + rl]      = acc10[j];
            C[(size_t)(bm0 + mq + 16 + orow + j) * Nc + bn0 + nq + 16 + rl] = acc11[j];
        }
        // fused s/d epilogue (exact fp32): block's 64 cols == head blockIdx.x
        const int C0 = bn0 + nq + rl, C1 = C0 + 16;
        const float a1c0 = a1v[C0], a1c1 = a1v[C1];
        const float a2c0 = a2v[C0], a2c1 = a2v[C1];
        float ps0[4], ps1[4], pd0[4], pd1[4];
        #pragma unroll
        for (int j = 0; j < 4; ++j) {
            ps0[j] = acc00[j] * a1c0 + acc01[j] * a1c1;
            ps1[j] = acc10[j] * a1c0 + acc11[j] * a1c1;
            pd0[j] = acc00[j] * a2c0 + acc01[j] * a2c1;
            pd1[j] = acc10[j] * a2c0 + acc11[j] * a2c1;
        }
        #pragma unroll
        for (int off = 1; off < 16; off <<= 1) {
            #pragma unroll
            for (int j = 0; j < 4; ++j) {
                ps0[j] += __shfl_xor(ps0[j], off);
                ps1[j] += __shfl_xor(ps1[j], off);
                pd0[j] += __shfl_xor(pd0[j], off);
                pd1[j] += __shfl_xor(pd1[j], off);
            }
        }
        float* eps = (float*)lds;
        if ((wid & 1) == 0 && rl == 0) {
            #pragma unroll
            for (int j = 0; j < 4; ++j) {
                eps[mq + orow + j]           = ps0[j];
                eps[mq + 16 + orow + j]      = ps1[j];
                eps[64 + mq + orow + j]      = pd0[j];
                eps[64 + mq + 16 + orow + j] = pd1[j];
            }
        }
        __syncthreads();
        if ((wid & 1) == 1 && rl == 0) {
            #pragma unroll
            for (int j = 0; j < 4; ++j) {
                const int t0 = mq + orow + j, t1 = t0 + 16;
                float* sh_ = sdst + (size_t)blockIdx.x * M;
                float* dh_ = ddst + (size_t)blockIdx.x * M;
                sh_[bm0 + t0] = ps0[j] + eps[t0];
                sh_[bm0 + t1] = ps1[j] + eps[t1];
                dh_[bm0 + t0] = pd0[j] + eps[64 + t0];
                dh_[bm0 + t1] = pd1[j] + eps[64 + t1];
            }
        }
    }
}

// ---- attention + aggregate + ELU. One block (256 thr) per row, single pass.
// MODE 0 (layer 1, H=8): Wh f32 in; s/d = [H][N]; write hi/lo bf16 hcat;
//                        epilogue: s2[row]=hcat·wo1, d2[row]=hcat·wo2.
// MODE 1 (layer 2, H=1): hcat hi/lo bf16 in; s/d = s2/d2 scalars; ELU'd
//                        aggregate written as hi/lo bf16 (agg2, feeds gemm2)...
//   NOTE: layer-2 aggregate has NO inner ELU (concat=False) — raw agg written.
template<int H, int MODE>
__global__ __launch_bounds__(256) void attn_kernel(
        const float* __restrict__ Wh,
        const unsigned short* __restrict__ Whi, const unsigned short* __restrict__ Wlo,
        const float* __restrict__ s, const float* __restrict__ d,
        const unsigned short* __restrict__ nbr, const int* __restrict__ deg,
        unsigned short* __restrict__ ohi, unsigned short* __restrict__ olo,
        const float* __restrict__ wo1, const float* __restrict__ wo2,
        float* __restrict__ s2, float* __restrict__ d2, int N) {
    constexpr int F = 512, NH = F / H, CAP = 512, GS = 256 / H;
    __shared__ int nb[CAP];
    __shared__ float p[H][CAP];
    __shared__ float lred[H];
    __shared__ float red[4];
    __shared__ float redS[4], redD[4];
    const int t = threadIdx.x, lane = t & 63, wid = t >> 6, row = blockIdx.x;
    const int M = deg[row];
    for (int j = t; j < M; j += 256) nb[j] = nbr[(size_t)row * 512 + j];
    __syncthreads();
    const int h = t / GS, sub = t % GS;
    const float sh = (MODE == 0) ? s[h * N + row] : s[row];
    float lm = -INFINITY;
    for (int j = sub; j < M; j += GS) {
        float dv = (MODE == 0) ? d[h * N + nb[j]] : d[nb[j]];
        float e = sh + dv;
        e = e > 0.f ? e : 0.2f * e;
        p[h][j] = e;
        lm = fmaxf(lm, e);
    }
    if constexpr (GS <= 64) {
        #pragma unroll
        for (int off = GS / 2; off; off >>= 1) lm = fmaxf(lm, __shfl_xor(lm, off));
    } else {
        #pragma unroll
        for (int off = 32; off; off >>= 1) lm = fmaxf(lm, __shfl_xor(lm, off));
        if (lane == 0) red[t >> 6] = lm;
        __syncthreads();
        lm = fmaxf(fmaxf(red[0], red[1]), fmaxf(red[2], red[3]));
    }
    float ls = 0.f;
    for (int j = sub; j < M; j += GS) {
        float pe = expf(p[h][j] - lm);
        p[h][j] = pe;
        ls += pe;
    }
    if constexpr (GS <= 64) {
        #pragma unroll
        for (int off = GS / 2; off; off >>= 1) ls += __shfl_xor(ls, off);
    } else {
        #pragma unroll
        for (int off = 32; off; off >>= 1) ls += __shfl_xor(ls, off);
        __syncthreads();
        if (lane == 0) red[t >> 6] = ls;
        __syncthreads();
        ls = red[0] + red[1] + red[2] + red[3];
    }
    if (sub == 0) lred[h] = ls;
    __syncthreads();
    const int c = 2 * t;
    const int hc = c / NH;
    const float inv = 1.f / lred[hc];
    float ax = 0.f, ay = 0.f;
    if constexpr (MODE == 0) {
        const float* base = Wh + c;
        #pragma unroll 4
        for (int j = 0; j < M; ++j) {
            float pw = p[hc][j];
            const float2 w = *(const float2*)(base + (size_t)nb[j] * F);
            ax += pw * w.x; ay += pw * w.y;
        }
    } else {
        const unsigned short* bh = Whi + c;
        const unsigned short* bl = Wlo + c;
        #pragma unroll 4
        for (int j = 0; j < M; ++j) {
            float pw = p[hc][j];
            const size_t o = (size_t)nb[j] * F;
            ushort2 hv = *(const ushort2*)(bh + o);
            ushort2 lv = *(const ushort2*)(bl + o);
            ax += pw * (bf2f(hv.x) + bf2f(lv.x));
            ay += pw * (bf2f(hv.y) + bf2f(lv.y));
        }
    }
    ax *= inv; ay *= inv;
    if constexpr (MODE == 0) {            // per-head ELU (concat=True)
        ax = ax > 0.f ? ax : expm1f(ax);
        ay = ay > 0.f ? ay : expm1f(ay);
    }
    {
        unsigned short hx, lx, hy, ly;
        split2(ax, hx, lx); split2(ay, hy, ly);
        ushort2 hv, lv;
        hv.x = hx; hv.y = hy; lv.x = lx; lv.y = ly;
        *(ushort2*)(ohi + (size_t)row * F + c) = hv;
        *(ushort2*)(olo + (size_t)row * F + c) = lv;
    }
    if constexpr (MODE == 0) {            // s2/d2 epilogue: hcat·wo1, hcat·wo2
        const float2 w1 = *(const float2*)(wo1 + c);
        const float2 w2 = *(const float2*)(wo2 + c);
        float psv = ax * w1.x + ay * w1.y;
        float pdv = ax * w2.x + ay * w2.y;
        #pragma unroll
        for (int off = 32; off; off >>= 1) {
            psv += __shfl_xor(psv, off);
            pdv += __shfl_xor(pdv, off);
        }
        if (lane == 0) { redS[wid] = psv; redD[wid] = pdv; }
        __syncthreads();
        if (t == 0) {
            s2[row] = (redS[0] + redS[1]) + (redS[2] + redS[3]);
            d2[row] = (redD[0] + redD[1]) + (redD[2] + redD[3]);
        }
    }
}

extern "C" void kernel_launch(void* const* d_in, const int* in_sizes, int n_in,
                              void* d_out, int out_size, void* d_ws, size_t ws_size,
                              hipStream_t stream) {
    const float* x   = (const float*)d_in[0];
    const float* adj = (const float*)d_in[2];
    const float* Ws  = (const float*)d_in[3];
    const float* a1  = (const float*)d_in[4];   // [H][64] flat, c = h*64+k
    const float* a2  = (const float*)d_in[5];
    const float* Wo  = (const float*)d_in[6];
    const float* ao1 = (const float*)d_in[7];   // [512]
    const float* ao2 = (const float*)d_in[8];
    float* out = (float*)d_out;
    const int N = GN;

    float* ws    = (float*)d_ws;
    float* Wh    = ws;                    // 4096*512 f32
    float* sbuf  = Wh + 2097152;          // 8*4096
    float* dbuf  = sbuf + 32768;          // 8*4096
    float* s2b   = dbuf + 32768;          // 4096
    float* d2b   = s2b + 4096;            // 4096
    float* wo1v  = d2b + 4096;            // 512
    float* wo2v  = wo1v + 512;            // 512
    unsigned short* nbrs = (unsigned short*)(wo2v + 512);    // 4096*512 u16
    int*            deg  = (int*)(nbrs + 2097152);           // 4096 i32
    unsigned short* xhi  = (unsigned short*)(deg + 4096);    // 4096*512 u16
    unsigned short* xlo  = xhi + 2097152;
    unsigned short* hch  = xlo + 2097152;                    // hcat hi
    unsigned short* hcl  = hch + 2097152;                    // hcat lo
    unsigned short* a2h  = hcl + 2097152;                    // agg2 hi
    unsigned short* a2l  = a2h + 2097152;                    // agg2 lo
    unsigned short* wshi = a2l + 2097152;                    // 512*512
    unsigned short* wslo = wshi + 262144;
    unsigned short* wohi = wslo + 262144;
    unsigned short* wolo = wohi + 262144;

    hipLaunchKernelGGL(prep, dim3(6280), dim3(256), 0, stream,
                       adj, Ws, Wo, x, ao1, ao2, nbrs, deg,
                       wshi, wslo, wohi, wolo, xhi, xlo, wo1v, wo2v, N);
    hipLaunchKernelGGL((gemm_3t<0>), dim3(8, 64), dim3(256), 0, stream,
                       xhi, xlo, wshi, wslo, a1, a2, Wh, sbuf, dbuf, 4096, 512, 512);
    hipLaunchKernelGGL((attn_kernel<8, 0>), dim3(4096), dim3(256), 0, stream,
                       Wh, (const unsigned short*)nullptr, (const unsigned short*)nullptr,
                       sbuf, dbuf, nbrs, deg, hch, hcl, wo1v, wo2v, s2b, d2b, N);
    hipLaunchKernelGGL((attn_kernel<1, 1>), dim3(4096), dim3(256), 0, stream,
                       (const float*)nullptr, hch, hcl, s2b, d2b, nbrs, deg,
                       a2h, a2l, (const float*)nullptr, (const float*)nullptr,
                       (float*)nullptr, (float*)nullptr, N);
    hipLaunchKernelGGL((gemm_3t<1>), dim3(8, 64), dim3(256), 0, stream,
                       a2h, a2l, wohi, wolo, (const float*)nullptr, (const float*)nullptr,
                       out, (float*)nullptr, (float*)nullptr, 4096, 512, 512);
}

// Round 8
// 114.981 us; speedup vs baseline: 1.0308x; 1.0308x over previous
//
#include <hip/hip_runtime.h>
#include <hip/hip_bf16.h>
#include <math.h>

// GAT forward, N=4096, F=512, H=8, NH=64.
// Round 8: revert to round-6 dataflow (measured 112.3); upgrade GEMM to
// 128x64 tile / 512 threads / 8 waves / 96KB dbuf LDS / grid 256 = 1 block/CU.

#define GN 4096
#define GF 512

typedef __attribute__((ext_vector_type(8))) short bf16x8;
typedef __attribute__((ext_vector_type(4))) float f32x4;

__device__ inline unsigned short f2bf(float f) {
    unsigned u = __float_as_uint(f);
    return (unsigned short)((u + 0x7fffu + ((u >> 16) & 1u)) >> 16);
}
__device__ inline float bf2f(unsigned short h) {
    return __uint_as_float((unsigned)h << 16);
}
__device__ inline void split2(float v, unsigned short& h, unsigned short& l) {
    h = f2bf(v);
    l = f2bf(v - bf2f(h));
}
__device__ inline void gl16(const void* g, void* l) {
    __builtin_amdgcn_global_load_lds((const __attribute__((address_space(1))) unsigned int*)g,
                                     (__attribute__((address_space(3))) unsigned int*)l, 16, 0, 0);
}

// ---- fused prep: extract_nbrs + LDS-transposed packs of Ws/Wo + split x ----
// grid = 4096 (extract) + 64 (Ws) + 64 (Wo) + 2048 (x split) = 6272
__global__ __launch_bounds__(256) void prep(
        const float* __restrict__ adj, const float* __restrict__ Ws,
        const float* __restrict__ Wo, const float* __restrict__ x,
        unsigned short* __restrict__ nbr, int* __restrict__ deg,
        unsigned short* __restrict__ wshi, unsigned short* __restrict__ wslo,
        unsigned short* __restrict__ wohi, unsigned short* __restrict__ wolo,
        unsigned short* __restrict__ xhi, unsigned short* __restrict__ xlo, int N) {
    __shared__ int wtot[4];
    __shared__ int wbase[4];
    __shared__ float T[64][65];
    int b = blockIdx.x;
    const int t = threadIdx.x;
    if (b < 4096) {                       // neighbor extraction, row = b
        const int lane = t & 63, wid = t >> 6, row = b;
        const float4* arow = (const float4*)(adj + (size_t)row * N);
        unsigned mask16 = 0;
        #pragma unroll
        for (int q = 0; q < 4; ++q) {
            float4 v = arow[t * 4 + q];
            if (v.x > 0.f) mask16 |= 1u << (q * 4 + 0);
            if (v.y > 0.f) mask16 |= 1u << (q * 4 + 1);
            if (v.z > 0.f) mask16 |= 1u << (q * 4 + 2);
            if (v.w > 0.f) mask16 |= 1u << (q * 4 + 3);
        }
        int cnt = __popc(mask16);
        int inc = cnt;
        #pragma unroll
        for (int off = 1; off < 64; off <<= 1) {
            int nv = __shfl_up(inc, off);
            if (lane >= off) inc += nv;
        }
        if (lane == 63) wtot[wid] = inc;
        __syncthreads();
        if (t == 0) {
            int s = 0;
            #pragma unroll
            for (int w = 0; w < 4; ++w) { wbase[w] = s; s += wtot[w]; }
            deg[row] = s;
        }
        __syncthreads();
        int base = wbase[wid] + inc - cnt;
        unsigned short* dst = nbr + (size_t)row * 512 + base;
        int col0 = t * 16;
        int k = 0;
        while (mask16) {
            int bi = __ffs(mask16) - 1;
            mask16 &= mask16 - 1;
            dst[k++] = (unsigned short)(col0 + bi);
        }
        return;
    }
    b -= 4096;
    if (b < 64) {                         // Ws[h][f][k] -> Bt[h*64+k][f], tiled
        const int h = b >> 3, f0 = (b & 7) * 64;
        #pragma unroll
        for (int i = 0; i < 16; ++i) {
            int idx = i * 256 + t;
            int fr = idx >> 6, k = idx & 63;
            T[fr][k] = Ws[h * 32768 + (f0 + fr) * 64 + k];
        }
        __syncthreads();
        #pragma unroll
        for (int i = 0; i < 16; ++i) {
            int idx = i * 256 + t;
            int k = idx >> 6, fr = idx & 63;
            unsigned short hh, ll;
            split2(T[fr][k], hh, ll);
            size_t dst = (size_t)(h * 64 + k) * 512 + f0 + fr;
            wshi[dst] = hh; wslo[dst] = ll;
        }
        return;
    }
    b -= 64;
    if (b < 64) {                         // Wo[f][c] -> Bt[c][f], tiled
        const int c0 = (b >> 3) * 64, f0 = (b & 7) * 64;
        #pragma unroll
        for (int i = 0; i < 16; ++i) {
            int idx = i * 256 + t;
            int fr = idx >> 6, k = idx & 63;
            T[fr][k] = Wo[(size_t)(f0 + fr) * 512 + c0 + k];
        }
        __syncthreads();
        #pragma unroll
        for (int i = 0; i < 16; ++i) {
            int idx = i * 256 + t;
            int k = idx >> 6, fr = idx & 63;
            unsigned short hh, ll;
            split2(T[fr][k], hh, ll);
            size_t dst = (size_t)(c0 + k) * 512 + f0 + fr;
            wohi[dst] = hh; wolo[dst] = ll;
        }
        return;
    }
    b -= 64;
    {                                     // split x -> hi/lo, 2048 blocks
        int i = b * 256 + t;              // [0, 524288)
        float4 v = ((const float4*)x)[i];
        ushort4 h, l;
        split2(v.x, h.x, l.x); split2(v.y, h.y, l.y);
        split2(v.z, h.z, l.z); split2(v.w, h.w, l.w);
        ((ushort4*)xhi)[i] = h;
        ((ushort4*)xlo)[i] = l;
    }
}

// ---- MFMA GEMM: C = A@B; A hi/lo [M][K], B hi/lo [Nc][K].
// 128x64 tile, 512 threads (8 waves, 4m x 2n of 32x32), BK=64, dbuf LDS 96KB,
// 3-term bf16 split, both-sides XOR swizzle. Grid (Nc/64, M/128) = (8,32).
// Epilogue per-row dots with a1v/a2v over this block's 64 cols:
//   PART=false: block cols == head blockIdx.x -> s/d[blockIdx.x*M + row].
//   PART=true:  64-col partial -> spart/dpart[row*8 + blockIdx.x].
template<bool PART>
__global__ __launch_bounds__(512) void gemm_3t(
        const unsigned short* __restrict__ Ahi, const unsigned short* __restrict__ Alo,
        const unsigned short* __restrict__ Bhi, const unsigned short* __restrict__ Blo,
        const float* __restrict__ a1v, const float* __restrict__ a2v,
        float* __restrict__ C, float* __restrict__ sdst, float* __restrict__ ddst,
        int M, int K, int Nc) {
    __shared__ char lds[98304];           // 2 x 48KB: Ah[16K]|Al[16K]|Bh[8K]|Bl[8K]
    const int t = threadIdx.x, lane = t & 63, wid = t >> 6;
    const int bm0 = blockIdx.y * 128, bn0 = blockIdx.x * 64;
    const int r0 = t >> 3;                // 0..63
    const int sc8 = (((t & 7) ^ (r0 & 7)) << 3);   // swizzled source chunk, elems
    const size_t aoff = (size_t)(bm0 + r0) * K + sc8;
    const size_t boff = (size_t)(bn0 + r0) * K + sc8;
    const size_t a64  = (size_t)64 * K;

    auto stage = [&](char* dst, int k0) {
        gl16(Ahi + aoff + k0,       dst + 0 * 8192 + t * 16);   // Ah rows 0-63
        gl16(Ahi + aoff + a64 + k0, dst + 1 * 8192 + t * 16);   // Ah rows 64-127
        gl16(Alo + aoff + k0,       dst + 2 * 8192 + t * 16);
        gl16(Alo + aoff + a64 + k0, dst + 3 * 8192 + t * 16);
        gl16(Bhi + boff + k0,       dst + 4 * 8192 + t * 16);   // Bh rows 0-63
        gl16(Blo + boff + k0,       dst + 5 * 8192 + t * 16);
    };

    f32x4 acc[2][2] = {};
    const int wr = wid >> 1, wc = wid & 1;
    const int rl = lane & 15, hl = lane >> 4;
    const int swz = rl & 7;               // row&7 invariant across +16/+32 offsets

    auto compute = [&](const char* Lb) {
        const char* Ah_ = Lb;
        const char* Al_ = Lb + 16384;
        const char* Bh_ = Lb + 32768;
        const char* Bl_ = Lb + 40960;
        #pragma unroll
        for (int s = 0; s < 2; ++s) {
            const int ch = ((s * 4 + hl) ^ swz) * 16;
            const int ra0 = (wr * 32 + rl) * 128, ra1 = ra0 + 16 * 128;
            const int rb0 = (wc * 32 + rl) * 128, rb1 = rb0 + 16 * 128;
            bf16x8 A0h = *(const bf16x8*)(Ah_ + ra0 + ch);
            bf16x8 A1h = *(const bf16x8*)(Ah_ + ra1 + ch);
            bf16x8 A0l = *(const bf16x8*)(Al_ + ra0 + ch);
            bf16x8 A1l = *(const bf16x8*)(Al_ + ra1 + ch);
            bf16x8 B0h = *(const bf16x8*)(Bh_ + rb0 + ch);
            bf16x8 B1h = *(const bf16x8*)(Bh_ + rb1 + ch);
            bf16x8 B0l = *(const bf16x8*)(Bl_ + rb0 + ch);
            bf16x8 B1l = *(const bf16x8*)(Bl_ + rb1 + ch);
            acc[0][0] = __builtin_amdgcn_mfma_f32_16x16x32_bf16(A0h, B0h, acc[0][0], 0, 0, 0);
            acc[0][1] = __builtin_amdgcn_mfma_f32_16x16x32_bf16(A0h, B1h, acc[0][1], 0, 0, 0);
            acc[1][0] = __builtin_amdgcn_mfma_f32_16x16x32_bf16(A1h, B0h, acc[1][0], 0, 0, 0);
            acc[1][1] = __builtin_amdgcn_mfma_f32_16x16x32_bf16(A1h, B1h, acc[1][1], 0, 0, 0);
            acc[0][0] = __builtin_amdgcn_mfma_f32_16x16x32_bf16(A0h, B0l, acc[0][0], 0, 0, 0);
            acc[0][1] = __builtin_amdgcn_mfma_f32_16x16x32_bf16(A0h, B1l, acc[0][1], 0, 0, 0);
            acc[1][0] = __builtin_amdgcn_mfma_f32_16x16x32_bf16(A1h, B0l, acc[1][0], 0, 0, 0);
            acc[1][1] = __builtin_amdgcn_mfma_f32_16x16x32_bf16(A1h, B1l, acc[1][1], 0, 0, 0);
            acc[0][0] = __builtin_amdgcn_mfma_f32_16x16x32_bf16(A0l, B0h, acc[0][0], 0, 0, 0);
            acc[0][1] = __builtin_amdgcn_mfma_f32_16x16x32_bf16(A0l, B1h, acc[0][1], 0, 0, 0);
            acc[1][0] = __builtin_amdgcn_mfma_f32_16x16x32_bf16(A1l, B0h, acc[1][0], 0, 0, 0);
            acc[1][1] = __builtin_amdgcn_mfma_f32_16x16x32_bf16(A1l, B1h, acc[1][1], 0, 0, 0);
        }
    };

    stage(lds, 0);
    __syncthreads();
    const int NT = K / 64;                // 8 steps
    for (int st = 0; st < NT; ++st) {
        char* cur = lds + (st & 1) * 49152;
        if (st + 1 < NT) stage(lds + ((st + 1) & 1) * 49152, (st + 1) * 64);
        compute(cur);
        __syncthreads();
    }

    const int orow = hl * 4;
    #pragma unroll
    for (int mi = 0; mi < 2; ++mi) {
        #pragma unroll
        for (int j = 0; j < 4; ++j) {
            const size_t row = bm0 + wr * 32 + mi * 16 + orow + j;
            C[row * Nc + bn0 + wc * 32 + rl]      = acc[mi][0][j];
            C[row * Nc + bn0 + wc * 32 + 16 + rl] = acc[mi][1][j];
        }
    }

    // ---- fused s/d epilogue (exact fp32, same acc values) ----
    const int C0 = bn0 + wc * 32 + rl, C1 = C0 + 16;
    const float a1c0 = a1v[C0], a1c1 = a1v[C1];
    const float a2c0 = a2v[C0], a2c1 = a2v[C1];
    float ps[2][4], pd[2][4];
    #pragma unroll
    for (int mi = 0; mi < 2; ++mi)
        #pragma unroll
        for (int j = 0; j < 4; ++j) {
            ps[mi][j] = acc[mi][0][j] * a1c0 + acc[mi][1][j] * a1c1;
            pd[mi][j] = acc[mi][0][j] * a2c0 + acc[mi][1][j] * a2c1;
        }
    #pragma unroll
    for (int off = 1; off < 16; off <<= 1) {
        #pragma unroll
        for (int mi = 0; mi < 2; ++mi)
            #pragma unroll
            for (int j = 0; j < 4; ++j) {
                ps[mi][j] += __shfl_xor(ps[mi][j], off);
                pd[mi][j] += __shfl_xor(pd[mi][j], off);
            }
    }
    float* eps = (float*)lds;             // eps[2][128][2] : [s|d][row][wc]
    if (rl == 0) {
        #pragma unroll
        for (int mi = 0; mi < 2; ++mi)
            #pragma unroll
            for (int j = 0; j < 4; ++j) {
                const int row = wr * 32 + mi * 16 + orow + j;
                eps[(0 * 128 + row) * 2 + wc] = ps[mi][j];
                eps[(1 * 128 + row) * 2 + wc] = pd[mi][j];
            }
    }
    __syncthreads();
    if (t < 128) {
        const int row = t;
        const float sv = eps[(0 * 128 + row) * 2 + 0] + eps[(0 * 128 + row) * 2 + 1];
        const float dv = eps[(1 * 128 + row) * 2 + 0] + eps[(1 * 128 + row) * 2 + 1];
        if constexpr (PART) {
            sdst[(size_t)(bm0 + row) * 8 + blockIdx.x] = sv;
            ddst[(size_t)(bm0 + row) * 8 + blockIdx.x] = dv;
        } else {
            sdst[(size_t)blockIdx.x * M + bm0 + row] = sv;
            ddst[(size_t)blockIdx.x * M + bm0 + row] = dv;
        }
    }
}

// ---- attention + aggregate + ELU. One block (256 thr) per row, single pass. ----
// SPLIT: write hi/lo bf16 (feeds next MFMA GEMM); else write f32.
// PART8: s/d are [row][8] per-bn partials (layer 2); else s/d are [H][N].
template<int H, bool SPLIT, bool PART8>
__global__ __launch_bounds__(256) void attn_kernel(
        const float* __restrict__ Wh, const float* __restrict__ s,
        const float* __restrict__ d, const unsigned short* __restrict__ nbr,
        const int* __restrict__ deg, float* __restrict__ out,
        unsigned short* __restrict__ ohi, unsigned short* __restrict__ olo, int N) {
    constexpr int F = 512, NH = F / H, CAP = 512, GS = 256 / H;
    __shared__ int nb[CAP];
    __shared__ float p[H][CAP];
    __shared__ float lred[H];
    __shared__ float red[4];
    const int t = threadIdx.x, lane = t & 63, row = blockIdx.x;
    const int M = deg[row];
    for (int j = t; j < M; j += 256) nb[j] = nbr[(size_t)row * 512 + j];
    __syncthreads();
    const int h = t / GS, sub = t % GS;
    float sh;
    if constexpr (PART8) {
        const float4* sp = (const float4*)(s + (size_t)row * 8);
        float4 s0 = sp[0], s1 = sp[1];
        sh = ((s0.x + s0.y) + (s0.z + s0.w)) + ((s1.x + s1.y) + (s1.z + s1.w));
    } else {
        sh = s[h * N + row];
    }
    float lm = -INFINITY;
    for (int j = sub; j < M; j += GS) {
        float dv;
        if constexpr (PART8) {
            const float4* dp = (const float4*)(d + (size_t)nb[j] * 8);
            float4 d0 = dp[0], d1 = dp[1];
            dv = ((d0.x + d0.y) + (d0.z + d0.w)) + ((d1.x + d1.y) + (d1.z + d1.w));
        } else {
            dv = d[h * N + nb[j]];
        }
        float e = sh + dv;
        e = e > 0.f ? e : 0.2f * e;
        p[h][j] = e;
        lm = fmaxf(lm, e);
    }
    if constexpr (GS <= 64) {
        #pragma unroll
        for (int off = GS / 2; off; off >>= 1) lm = fmaxf(lm, __shfl_xor(lm, off));
    } else {
        #pragma unroll
        for (int off = 32; off; off >>= 1) lm = fmaxf(lm, __shfl_xor(lm, off));
        if (lane == 0) red[t >> 6] = lm;
        __syncthreads();
        lm = fmaxf(fmaxf(red[0], red[1]), fmaxf(red[2], red[3]));
    }
    float ls = 0.f;
    for (int j = sub; j < M; j += GS) {
        float pe = expf(p[h][j] - lm);
        p[h][j] = pe;
        ls += pe;
    }
    if constexpr (GS <= 64) {
        #pragma unroll
        for (int off = GS / 2; off; off >>= 1) ls += __shfl_xor(ls, off);
    } else {
        #pragma unroll
        for (int off = 32; off; off >>= 1) ls += __shfl_xor(ls, off);
        __syncthreads();
        if (lane == 0) red[t >> 6] = ls;
        __syncthreads();
        ls = red[0] + red[1] + red[2] + red[3];
    }
    if (sub == 0) lred[h] = ls;
    __syncthreads();
    const int c = 2 * t;
    const int hc = c / NH;
    const float inv = 1.f / lred[hc];
    const float* base = Wh + c;
    float ax = 0.f, ay = 0.f;
    #pragma unroll 4
    for (int j = 0; j < M; ++j) {
        float pw = p[hc][j];
        const float2 w = *(const float2*)(base + (size_t)nb[j] * F);
        ax += pw * w.x; ay += pw * w.y;
    }
    ax *= inv; ay *= inv;
    ax = ax > 0.f ? ax : expm1f(ax);
    ay = ay > 0.f ? ay : expm1f(ay);
    if constexpr (SPLIT) {
        unsigned short hx, lx, hy, ly;
        split2(ax, hx, lx); split2(ay, hy, ly);
        ushort2 hv, lv;
        hv.x = hx; hv.y = hy; lv.x = lx; lv.y = ly;
        *(ushort2*)(ohi + (size_t)row * F + c) = hv;
        *(ushort2*)(olo + (size_t)row * F + c) = lv;
    } else {
        float2 o; o.x = ax; o.y = ay;
        *(float2*)(out + (size_t)row * F + c) = o;
    }
}

extern "C" void kernel_launch(void* const* d_in, const int* in_sizes, int n_in,
                              void* d_out, int out_size, void* d_ws, size_t ws_size,
                              hipStream_t stream) {
    const float* x   = (const float*)d_in[0];
    const float* adj = (const float*)d_in[2];
    const float* Ws  = (const float*)d_in[3];
    const float* a1  = (const float*)d_in[4];   // [H][64] flat, c = h*64+k
    const float* a2  = (const float*)d_in[5];
    const float* Wo  = (const float*)d_in[6];
    const float* ao1 = (const float*)d_in[7];   // [512]
    const float* ao2 = (const float*)d_in[8];
    float* out = (float*)d_out;
    const int N = GN;

    float* ws    = (float*)d_ws;
    float* Wh    = ws;                    // 4096*512 f32
    float* Who   = Wh + 2097152;          // 4096*512 f32
    float* sbuf  = Who + 2097152;         // 8*4096
    float* dbuf  = sbuf + 32768;          // 8*4096
    float* spart = dbuf + 32768;          // 4096*8
    float* dpart = spart + 32768;         // 4096*8
    unsigned short* nbrs = (unsigned short*)(dpart + 32768); // 4096*512 u16
    int*            deg  = (int*)(nbrs + 2097152);           // 4096 i32
    unsigned short* xhi  = (unsigned short*)(deg + 4096);    // 4096*512 u16
    unsigned short* xlo  = xhi + 2097152;
    unsigned short* hch  = xlo + 2097152;                    // hcat hi
    unsigned short* hcl  = hch + 2097152;                    // hcat lo
    unsigned short* wshi = hcl + 2097152;                    // 512*512
    unsigned short* wslo = wshi + 262144;
    unsigned short* wohi = wslo + 262144;
    unsigned short* wolo = wohi + 262144;

    hipLaunchKernelGGL(prep, dim3(6272), dim3(256), 0, stream,
                       adj, Ws, Wo, x, nbrs, deg, wshi, wslo, wohi, wolo, xhi, xlo, N);
    hipLaunchKernelGGL((gemm_3t<false>), dim3(8, 32), dim3(512), 0, stream,
                       xhi, xlo, wshi, wslo, a1, a2, Wh, sbuf, dbuf, 4096, 512, 512);
    hipLaunchKernelGGL((attn_kernel<8, true, false>), dim3(4096), dim3(256), 0, stream,
                       Wh, sbuf, dbuf, nbrs, deg, (float*)nullptr, hch, hcl, N);
    hipLaunchKernelGGL((gemm_3t<true>), dim3(8, 32), dim3(512), 0, stream,
                       hch, hcl, wohi, wolo, ao1, ao2, Who, spart, dpart, 4096, 512, 512);
    hipLaunchKernelGGL((attn_kernel<1, false, true>), dim3(4096), dim3(256), 0, stream,
                       Who, spart, dpart, nbrs, deg, out, (unsigned short*)nullptr,
                       (unsigned short*)nullptr, N);
}